// Round 11
// baseline (1907.495 us; speedup 1.0000x reference)
//
#include <hip/hip_runtime.h>
#include <hip/hip_bf16.h>
#include <cstdint>
#include <cstddef>

#define BB 256
#define TT 20
#define NOBJ 36
#define OBJD 2048
#define ATTD 1024
#define DECD 1024
#define VOCAB 10000
#define NHC   7168     // Hcat: 1024 att2 | 2048 gate | 4096 Whh-gates (interleaved)
#define VOCP  10240    // vocab padded to 80 tiles of 128 (8 XCDs x 10 panels)

typedef unsigned short u16;
typedef __attribute__((ext_vector_type(8))) short short8v;
typedef __attribute__((ext_vector_type(4))) float f32x4;

__device__ inline u16 f2bf(float f) {
    __hip_bfloat16 h = __float2bfloat16(f);
    return *reinterpret_cast<u16*>(&h);
}
__device__ inline float bu(u16 u) {
    union { unsigned int i; float f; } x;
    x.i = ((unsigned int)u) << 16;
    return x.f;
}
__device__ inline float sigf(float x) { return 1.f / (1.f + expf(-x)); }

// async global->LDS, 16B per lane (wave-uniform LDS base + lane*16)
__device__ inline void gload16(const u16* g, u16* l) {
    __builtin_amdgcn_global_load_lds(
        (const __attribute__((address_space(1))) unsigned int*)g,
        (__attribute__((address_space(3))) unsigned int*)l, 16, 0, 0);
}

// counted tile-wait: allow min(rem, DEPTH-1) tiles (4 loads each) outstanding
template<int DEPTH>
__device__ __forceinline__ void wait_tiles(int rem) {
    const int r = rem < DEPTH - 1 ? rem : DEPTH - 1;
    switch (r) {
        case 0: asm volatile("s_waitcnt vmcnt(0)" ::: "memory"); break;
        case 1: asm volatile("s_waitcnt vmcnt(4)" ::: "memory"); break;
        case 2: asm volatile("s_waitcnt vmcnt(8)" ::: "memory"); break;
        case 3: asm volatile("s_waitcnt vmcnt(12)" ::: "memory"); break;
        case 4: asm volatile("s_waitcnt vmcnt(16)" ::: "memory"); break;
        case 5: asm volatile("s_waitcnt vmcnt(20)" ::: "memory"); break;
        case 6: asm volatile("s_waitcnt vmcnt(24)" ::: "memory"); break;
        default: asm volatile("s_waitcnt vmcnt(28)" ::: "memory"); break;
    }
}

// ---------------------------------------------------------------------------
// Sort: stable descending argsort of lengths (O(B^2), one block)
// ---------------------------------------------------------------------------
__global__ __launch_bounds__(256) void sort_kernel(
    const int* __restrict__ lens, int* __restrict__ sidx, int* __restrict__ slen,
    int* __restrict__ cnt, float* __restrict__ out_len, float* __restrict__ out_sind)
{
    __shared__ int L[BB];
    __shared__ int SL[BB];
    const int i = threadIdx.x;
    const int li = lens[i];
    L[i] = li;
    __syncthreads();
    int r = 0;
    for (int j = 0; j < BB; ++j) {
        const int lj = L[j];
        if (lj > li || (lj == li && j < i)) r++;
    }
    sidx[r] = i;
    slen[r] = li;
    SL[r] = li;
    out_sind[r] = (float)i;
    out_len[r]  = (float)li;
    __syncthreads();
    if (i < TT) {
        int cc = 0;
        for (int b = 0; b < BB; ++b) cc += (SL[b] > i);
        cnt[i] = cc;
    }
}

__global__ __launch_bounds__(256) void meta_kernel(
    const int* __restrict__ caps, const int* __restrict__ sidx,
    float* __restrict__ out_caps)
{
    const int idx = blockIdx.x * 256 + threadIdx.x;   // grid 20
    const int p = idx / TT, t = idx % TT;
    out_caps[idx] = (float)caps[sidx[p] * TT + t];
}

// gather objects in sorted order -> bf16 (9216 x 2048)
__global__ __launch_bounds__(256) void gather_objs(
    const float* __restrict__ objs, const int* __restrict__ sidx,
    u16* __restrict__ objsb)
{
    const int row = blockIdx.x;              // 0..9215
    const int b = row / NOBJ, n = row - b * NOBJ;
    const float* src = objs + ((size_t)sidx[b] * NOBJ + n) * OBJD;
    u16* dst = objsb + (size_t)row * OBJD;
    const int tid = threadIdx.x;
    #pragma unroll
    for (int j = 0; j < 2; ++j) {
        float4 v = ((const float4*)src)[tid + 256 * j];
        ushort4 s;
        s.x = f2bf(v.x); s.y = f2bf(v.y); s.z = f2bf(v.z); s.w = f2bf(v.w);
        ((ushort4*)dst)[tid + 256 * j] = s;
    }
}

// Whc = [Wda | Wfb | Whh gate-interleaved] (7168 x 1024) bf16 + bcat
__global__ __launch_bounds__(256) void convWhc(
    const float* __restrict__ Wda, const float* __restrict__ bda,
    const float* __restrict__ Wfb, const float* __restrict__ bfb,
    const float* __restrict__ Whh,
    u16* __restrict__ Wb, float* __restrict__ bcat)
{
    const int n = blockIdx.x;                // 0..7167
    const int tid = threadIdx.x;
    const float* src;
    float bb = 0.f;
    if (n < 1024)      { src = Wda + (size_t)n * 1024;          bb = bda[n]; }
    else if (n < 3072) { src = Wfb + (size_t)(n - 1024) * 1024; bb = bfb[n - 1024]; }
    else {
        const int loc = n - 3072, q = loc & 3, d = loc >> 2;   // col 3072+4d+q = h.Whh[q*1024+d]
        src = Whh + ((size_t)q * 1024 + d) * 1024;
    }
    float4 v = ((const float4*)src)[tid];
    ushort4 s;
    s.x = f2bf(v.x); s.y = f2bf(v.y); s.z = f2bf(v.z); s.w = f2bf(v.w);
    ((ushort4*)(Wb + (size_t)n * 1024))[tid] = s;
    if (tid == 0) bcat[n] = bb;
}

// Wfc padded (10240 x 1024) bf16
__global__ __launch_bounds__(256) void convWfc(
    const float* __restrict__ Wfc, u16* __restrict__ Wb)
{
    const int n = blockIdx.x;                // 0..10239
    const int tid = threadIdx.x;
    ushort4 s;
    if (n < VOCAB) {
        float4 v = ((const float4*)(Wfc + (size_t)n * 1024))[tid];
        s.x = f2bf(v.x); s.y = f2bf(v.y); s.z = f2bf(v.z); s.w = f2bf(v.w);
    } else { s.x = s.y = s.z = s.w = 0; }
    ((ushort4*)(Wb + (size_t)n * 1024))[tid] = s;
}

// Wih gate-interleaved rows (4096 x 3072) + bsum (interleaved b_ih + b_hh)
__global__ __launch_bounds__(256) void convWih(
    const float* __restrict__ Wih, const float* __restrict__ bih,
    const float* __restrict__ bhh, u16* __restrict__ Wb, float* __restrict__ bsum)
{
    const int n = blockIdx.x;                // 0..4095 ; n = 4d+q
    const int q = n & 3, d = n >> 2;
    const int tid = threadIdx.x;
    const float* src = Wih + ((size_t)q * 1024 + d) * 3072;
    u16* dst = Wb + (size_t)n * 3072;
    #pragma unroll
    for (int j = 0; j < 3; ++j) {
        float4 v = ((const float4*)src)[tid + 256 * j];
        ushort4 s;
        s.x = f2bf(v.x); s.y = f2bf(v.y); s.z = f2bf(v.z); s.w = f2bf(v.w);
        ((ushort4*)dst)[tid + 256 * j] = s;
    }
    if (tid == 0) bsum[n] = bih[q * 1024 + d] + bhh[q * 1024 + d];
}

// Wea (1024 x 2048) bf16
__global__ __launch_bounds__(256) void convWea(
    const float* __restrict__ Wea, u16* __restrict__ Wb)
{
    const int n = blockIdx.x;
    const int tid = threadIdx.x;
    const float* src = Wea + (size_t)n * OBJD;
    u16* dst = Wb + (size_t)n * OBJD;
    #pragma unroll
    for (int j = 0; j < 2; ++j) {
        float4 v = ((const float4*)src)[tid + 256 * j];
        ushort4 s;
        s.x = f2bf(v.x); s.y = f2bf(v.y); s.z = f2bf(v.z); s.w = f2bf(v.w);
        ((ushort4*)dst)[tid + 256 * j] = s;
    }
}

// X[t*B+b] bf16
__global__ __launch_bounds__(256) void embed_kernel(
    const float* __restrict__ enc, const int* __restrict__ caps,
    const float* __restrict__ emb, const int* __restrict__ sidx,
    u16* __restrict__ Xb)
{
    const int blk = blockIdx.x;     // grid T*B
    const int t = blk >> 8;
    const int b = blk & 255;
    const int sb = sidx[b];
    const float* src = (t == 0) ? (enc + (size_t)sb * DECD)
                                : (emb + (size_t)caps[sb * TT + (t - 1)] * DECD);
    const int tid = threadIdx.x;
    float4 v = ((const float4*)src)[tid];
    ushort4 s;
    s.x = f2bf(v.x); s.y = f2bf(v.y); s.z = f2bf(v.z); s.w = f2bf(v.w);
    ((ushort4*)(Xb + (size_t)blk * DECD))[tid] = s;
}

__global__ __launch_bounds__(256) void zero_c(float* __restrict__ c)
{
    ((float4*)c)[blockIdx.x * 256 + threadIdx.x] = make_float4(0.f, 0.f, 0.f, 0.f);
}

// Hcat(0) = broadcast bcat (h0 = 0)
__global__ __launch_bounds__(256) void hcat0_kernel(
    const float* __restrict__ bcat, float* __restrict__ Hcat)
{
    const int col4 = blockIdx.x * 256 + threadIdx.x;   // 0..1791
    const int m = blockIdx.y;
    ((float4*)(Hcat + (size_t)m * NHC))[col4] = ((const float4*)bcat)[col4];
}

// ---------------------------------------------------------------------------
// Shared 128x128xK GEMM core, DEPTH-deep pipelined (counted vmcnt), source-
// pre-swizzled global_load_lds (LDS linear) + swizzled ds_read_b128. K%32==0.
// SH layout: A slots [0, DEPTH*4096), B slots [DEPTH*4096, 2*DEPTH*4096).
// ---------------------------------------------------------------------------
template<int DEPTH>
__device__ __forceinline__ void gemm_core(u16* SH,
    const u16* __restrict__ A, int lda,
    const u16* __restrict__ B, int ldb,
    int K, int m0, int n0, f32x4 acc[4][4])
{
    u16* AsB = SH;
    u16* BsB = SH + DEPTH * 4096;
    const int tid = threadIdx.x;
    const int lane = tid & 63;
    const int w = tid >> 6;
    const int wr = w >> 1, wc = w & 1;

    const int r0 = (w * 2 + 0) * 16 + (lane >> 2);
    const int r1 = (w * 2 + 1) * 16 + (lane >> 2);
    const int s0 = (lane & 3) ^ ((r0 >> 1) & 3);
    const int s1 = (lane & 3) ^ ((r1 >> 1) & 3);
    const u16* gA0 = A + (size_t)(m0 + r0) * lda + s0 * 8;
    const u16* gA1 = A + (size_t)(m0 + r1) * lda + s1 * 8;
    const u16* gB0 = B + (size_t)(n0 + r0) * ldb + s0 * 8;
    const u16* gB1 = B + (size_t)(n0 + r1) * ldb + s1 * 8;
    const int la0 = (w * 2 + 0) * 512;
    const int la1 = (w * 2 + 1) * 512;

    int ia[4], ib[4];
    #pragma unroll
    for (int mi = 0; mi < 4; ++mi) {
        const int r = wr * 64 + mi * 16 + (lane & 15);
        ia[mi] = r * 32 + (((lane >> 4) ^ ((r >> 1) & 3)) << 3);
    }
    #pragma unroll
    for (int nj = 0; nj < 4; ++nj) {
        const int r = wc * 64 + nj * 16 + (lane & 15);
        ib[nj] = r * 32 + (((lane >> 4) ^ ((r >> 1) & 3)) << 3);
    }

    const int nk = K >> 5;
    #pragma unroll
    for (int p = 0; p < DEPTH; ++p) {
        if (p < nk) {
            const int ko = p * 32;
            gload16(gA0 + ko, AsB + p * 4096 + la0);
            gload16(gA1 + ko, AsB + p * 4096 + la1);
            gload16(gB0 + ko, BsB + p * 4096 + la0);
            gload16(gB1 + ko, BsB + p * 4096 + la1);
        }
    }
    int cur = 0;
    for (int it = 0; it < nk; ++it) {
        wait_tiles<DEPTH>(nk - 1 - it);
        __builtin_amdgcn_s_barrier();
        const u16* Asc = AsB + cur * 4096;
        const u16* Bsc = BsB + cur * 4096;
        short8v av[4], bv[4];
        #pragma unroll
        for (int mi = 0; mi < 4; ++mi) av[mi] = *(const short8v*)&Asc[ia[mi]];
        #pragma unroll
        for (int nj = 0; nj < 4; ++nj) bv[nj] = *(const short8v*)&Bsc[ib[nj]];
        __builtin_amdgcn_s_setprio(1);
        #pragma unroll
        for (int mi = 0; mi < 4; ++mi)
            #pragma unroll
            for (int nj = 0; nj < 4; ++nj)
                acc[mi][nj] = __builtin_amdgcn_mfma_f32_16x16x32_bf16(
                    av[mi], bv[nj], acc[mi][nj], 0, 0, 0);
        __builtin_amdgcn_s_setprio(0);
        __builtin_amdgcn_s_barrier();
        if (it + DEPTH < nk) {
            const int ko = (it + DEPTH) * 32;
            gload16(gA0 + ko, AsB + cur * 4096 + la0);
            gload16(gA1 + ko, AsB + cur * 4096 + la1);
            gload16(gB0 + ko, BsB + cur * 4096 + la0);
            gload16(gB1 + ko, BsB + cur * 4096 + la1);
        }
        cur = (cur == DEPTH - 1) ? 0 : cur + 1;
    }
}

// ---------------------------------------------------------------------------
// Generic GEMM kernel (f32 Cf or bf16 Cb). pairM: 1D grid, n=bid>>1, m=bid&1.
// cntp: skip whole tile when m0 >= *cntp.
// ---------------------------------------------------------------------------
template<int DEPTH>
__global__ __launch_bounds__(256) void gemm128(
    const u16* __restrict__ A, int lda,
    const u16* __restrict__ B, int ldb,
    const float* __restrict__ bias,
    float* __restrict__ Cf, u16* __restrict__ Cb, int ldc,
    int Nreal, int K, int pairM, const int* __restrict__ cntp)
{
    __shared__ __align__(16) u16 SH[2 * DEPTH * 4096];
    int nIdx, mIdx;
    if (pairM) { nIdx = blockIdx.x >> 1; mIdx = blockIdx.x & 1; }
    else       { nIdx = blockIdx.x;      mIdx = blockIdx.y; }
    const int m0 = mIdx * 128;
    const int n0 = nIdx * 128;
    if (cntp && m0 >= *cntp) return;

    f32x4 acc[4][4];
    #pragma unroll
    for (int i = 0; i < 4; ++i)
        #pragma unroll
        for (int j = 0; j < 4; ++j) acc[i][j] = (f32x4){0.f, 0.f, 0.f, 0.f};
    gemm_core<DEPTH>(SH, A, lda, B, ldb, K, m0, n0, acc);

    const int lane = threadIdx.x & 63, w = threadIdx.x >> 6;
    const int wr = w >> 1, wc = w & 1;
    #pragma unroll
    for (int mi = 0; mi < 4; ++mi) {
        const int mbase = m0 + wr * 64 + mi * 16 + ((lane >> 4) << 2);
        #pragma unroll
        for (int nj = 0; nj < 4; ++nj) {
            const int n = n0 + wc * 64 + nj * 16 + (lane & 15);
            if (n >= Nreal) continue;
            const float bval = bias ? bias[n] : 0.f;
            #pragma unroll
            for (int r = 0; r < 4; ++r) {
                const int m = mbase + r;
                const float v = acc[mi][nj][r] + bval;
                if (Cb) Cb[(size_t)m * ldc + n] = f2bf(v);
                else    Cf[(size_t)m * ldc + n] = v;
            }
        }
    }
}

// ---------------------------------------------------------------------------
// G2 GEMM + fused LSTM (DEPTH=8 pipeline, 128KB LDS, 1 block/CU).
// Grid 64: n = bid>>1 (0..31), m = bid&1.
// ---------------------------------------------------------------------------
__global__ __launch_bounds__(256) void g2l_kernel(
    const u16* __restrict__ aweb, const u16* __restrict__ Wihb,
    const u16* __restrict__ Gxb_t, const float* __restrict__ Hcat,
    float* __restrict__ c, u16* __restrict__ hb_t,
    const int* __restrict__ cntp)
{
    __shared__ __align__(16) u16 SH[2 * 8 * 4096];   // 128KB
    const int bid = blockIdx.x, tid = threadIdx.x;
    const int m0 = (bid & 1) * 128, n0 = (bid >> 1) * 128;
    const int act = *cntp;
    if (m0 >= act) return;

    f32x4 acc[4][4];
    #pragma unroll
    for (int i = 0; i < 4; ++i)
        #pragma unroll
        for (int j = 0; j < 4; ++j) acc[i][j] = (f32x4){0.f, 0.f, 0.f, 0.f};
    gemm_core<8>(SH, aweb, 2048, Wihb + 1024, 3072, 2048, m0, n0, acc);

    const int lane = tid & 63, w = tid >> 6;
    const int wr = w >> 1, wc = w & 1;
    float* patch = (float*)SH;   // 64 x 128 f32 = 32KB (gemm_core done)
    #pragma unroll
    for (int half = 0; half < 2; ++half) {
        __syncthreads();
        if (wr == half) {
            #pragma unroll
            for (int mi = 0; mi < 4; ++mi) {
                const int rbase = mi * 16 + ((lane >> 4) << 2);
                #pragma unroll
                for (int nj = 0; nj < 4; ++nj) {
                    const int col = wc * 64 + nj * 16 + (lane & 15);
                    #pragma unroll
                    for (int r = 0; r < 4; ++r)
                        patch[(rbase + r) * 128 + col] = acc[mi][nj][r];
                }
            }
        }
        __syncthreads();
        const int h0 = half * 64;
        #pragma unroll
        for (int p8 = 0; p8 < 8; ++p8) {
            const int idx = p8 * 256 + tid;
            const int row = idx >> 5, dl = idx & 31;
            const int b = m0 + h0 + row;
            if (b >= act) continue;
            const int d = (n0 >> 2) + dl;
            const float* pr = patch + row * 128 + dl * 4;
            float gi = pr[0], gf = pr[1], gg = pr[2], go = pr[3];
            const ushort4 xv = *(const ushort4*)(Gxb_t + (size_t)b * 4096 + n0 + dl * 4);
            gi += bu(xv.x); gf += bu(xv.y); gg += bu(xv.z); go += bu(xv.w);
            const float4 hv = *(const float4*)(Hcat + (size_t)b * NHC + 3072 + n0 + dl * 4);
            gi += hv.x; gf += hv.y; gg += hv.z; go += hv.w;
            float* cp = c + (size_t)b * 1024 + d;
            const float cn = sigf(gf) * cp[0] + sigf(gi) * tanhf(gg);
            const float hn = sigf(go) * tanhf(cn);
            cp[0] = cn;
            hb_t[(size_t)b * 1024 + d] = f2bf(hn);
        }
    }
}

// ---------------------------------------------------------------------------
// Batched predictions GEMM, XCD-aware: XCD = bid%8 (round-robin dispatch).
// XCD x owns n-panels [10x, 10x+10) (2.56MB, L2-resident) and streams A.
// Grid 3200 = 8 XCDs x 40 m-tiles x 10 panels.
// ---------------------------------------------------------------------------
__global__ __launch_bounds__(256) void preds_gemm(
    const u16* __restrict__ hball, const u16* __restrict__ Wfcb,
    const float* __restrict__ bfc, const int* __restrict__ cnt,
    float* __restrict__ outP)
{
    __shared__ __align__(16) u16 SH[2 * 3 * 4096];
    const int bid = blockIdx.x;              // 0..3199
    const int x = bid & 7;                   // XCD
    const int j = bid >> 3;                  // 0..399
    const int n0 = (x * 10 + (j % 10)) * 128;
    const int m0 = (j / 10) * 128;           // 0..5119 (row in hball)
    const int t = m0 >> 8;
    const int act = cnt[t];
    const int bbase = m0 & 255;

    f32x4 acc[4][4];
    #pragma unroll
    for (int i = 0; i < 4; ++i)
        #pragma unroll
        for (int jj = 0; jj < 4; ++jj) acc[i][jj] = (f32x4){0.f, 0.f, 0.f, 0.f};
    if (bbase < act)
        gemm_core<3>(SH, hball, 1024, Wfcb, 1024, 1024, m0, n0, acc);

    const int lane = threadIdx.x & 63, w = threadIdx.x >> 6;
    const int wr = w >> 1, wc = w & 1;
    #pragma unroll
    for (int mi = 0; mi < 4; ++mi) {
        const int mbase = bbase + wr * 64 + mi * 16 + ((lane >> 4) << 2);
        #pragma unroll
        for (int nj = 0; nj < 4; ++nj) {
            const int n = n0 + wc * 64 + nj * 16 + (lane & 15);
            if (n >= VOCAB) continue;
            const float bval = bfc[n];
            #pragma unroll
            for (int r = 0; r < 4; ++r) {
                const int b = mbase + r;
                outP[((size_t)b * TT + t) * VOCAB + n] =
                    (b < act) ? (acc[mi][nj][r] + bval) : 0.f;
            }
        }
    }
}

// ---------------------------------------------------------------------------
// Attention, z-split over obj dims: grid (B, 2). Wave-parallel softmax.
// ---------------------------------------------------------------------------
__global__ __launch_bounds__(256) void attn_kernel(
    const u16* __restrict__ att1b, const float* __restrict__ Hcat,
    const u16* __restrict__ objsb,
    const float* __restrict__ wfa, const float* __restrict__ bfa,
    const int* __restrict__ slen, int t,
    float* __restrict__ out_alph, u16* __restrict__ aweb)
{
    const int b = blockIdx.x, z = blockIdx.y, tid = threadIdx.x;
    const bool active = t < slen[b];
    if (!active) {
        if (z == 0 && tid < NOBJ)
            out_alph[((size_t)b * TT + t) * NOBJ + tid] = 0.f;
        return;
    }
    __shared__ float wred[4][40];
    __shared__ float es[40];
    __shared__ float alph[40];
    const int lane = tid & 63, w = tid >> 6;
    const float* hrow = Hcat + (size_t)b * NHC;
    const float4 h4 = ((const float4*)hrow)[tid];
    const float4 w4 = ((const float4*)wfa)[tid];
    const u16* a1base = att1b + (size_t)b * NOBJ * ATTD;

    float ep[NOBJ];
    #pragma unroll
    for (int n = 0; n < NOBJ; ++n) {
        ushort4 a4 = ((const ushort4*)(a1base + (size_t)n * ATTD))[tid];
        const float v0 = fmaxf(bu(a4.x) + h4.x, 0.f);
        const float v1 = fmaxf(bu(a4.y) + h4.y, 0.f);
        const float v2 = fmaxf(bu(a4.z) + h4.z, 0.f);
        const float v3 = fmaxf(bu(a4.w) + h4.w, 0.f);
        ep[n] = v0 * w4.x + v1 * w4.y + v2 * w4.z + v3 * w4.w;
    }
    #pragma unroll
    for (int n = 0; n < NOBJ; ++n) {
        float p = ep[n];
        #pragma unroll
        for (int off = 32; off > 0; off >>= 1) p += __shfl_down(p, off, 64);
        if (lane == 0) wred[w][n] = p;
    }
    __syncthreads();
    if (tid < NOBJ)
        es[tid] = wred[0][tid] + wred[1][tid] + wred[2][tid] + wred[3][tid] + bfa[0];
    __syncthreads();
    if (tid < 64) {
        float mv = (tid < NOBJ) ? es[tid] : -1e30f;
        #pragma unroll
        for (int off = 32; off > 0; off >>= 1) mv = fmaxf(mv, __shfl_xor(mv, off, 64));
        float e = (tid < NOBJ) ? expf(es[tid] - mv) : 0.f;
        float s = e;
        #pragma unroll
        for (int off = 32; off > 0; off >>= 1) s += __shfl_xor(s, off, 64);
        if (tid < NOBJ) alph[tid] = e / s;
    }
    __syncthreads();
    if (z == 0 && tid < NOBJ)
        out_alph[((size_t)b * TT + t) * NOBJ + tid] = alph[tid];

    float acc[4] = {0.f, 0.f, 0.f, 0.f};
    const u16* ob = objsb + (size_t)b * NOBJ * OBJD + z * 1024 + tid * 4;
    #pragma unroll 4
    for (int n = 0; n < NOBJ; ++n) {
        const ushort4 ov = *(const ushort4*)(ob + (size_t)n * OBJD);
        const float al = alph[n];
        acc[0] = fmaf(al, bu(ov.x), acc[0]);
        acc[1] = fmaf(al, bu(ov.y), acc[1]);
        acc[2] = fmaf(al, bu(ov.z), acc[2]);
        acc[3] = fmaf(al, bu(ov.w), acc[3]);
    }
    const float4 g0 = *(const float4*)(hrow + 1024 + z * 1024 + tid * 4);
    ushort4 st;
    st.x = f2bf(acc[0] * sigf(g0.x));
    st.y = f2bf(acc[1] * sigf(g0.y));
    st.z = f2bf(acc[2] * sigf(g0.z));
    st.w = f2bf(acc[3] * sigf(g0.w));
    *(ushort4*)&aweb[(size_t)b * 2048 + z * 1024 + tid * 4] = st;
}

// ---------------------------------------------------------------------------
extern "C" void kernel_launch(void* const* d_in, const int* in_sizes, int n_in,
                              void* d_out, int out_size, void* d_ws, size_t ws_size,
                              hipStream_t stream)
{
    const float* enc  = (const float*)d_in[0];
    const float* objs = (const float*)d_in[1];
    const int*   caps = (const int*)d_in[2];
    const int*   clen = (const int*)d_in[3];
    const float* emb  = (const float*)d_in[4];
    const float* Wea  = (const float*)d_in[5];
    const float* bea  = (const float*)d_in[6];
    const float* Wda  = (const float*)d_in[7];
    const float* bda  = (const float*)d_in[8];
    const float* wfa  = (const float*)d_in[9];
    const float* bfa  = (const float*)d_in[10];
    const float* Wfb  = (const float*)d_in[11];
    const float* bfb  = (const float*)d_in[12];
    const float* Wih  = (const float*)d_in[13];
    const float* Whh  = (const float*)d_in[14];
    const float* bih  = (const float*)d_in[15];
    const float* bhh  = (const float*)d_in[16];
    const float* Wfc  = (const float*)d_in[17];
    const float* bfc  = (const float*)d_in[18];

    float* outP     = (float*)d_out;                       // (B,T,V)
    float* out_caps = outP + (size_t)BB * TT * VOCAB;      // (B,T)
    float* out_len  = out_caps + BB * TT;                  // (B,)
    float* out_alph = out_len + BB;                        // (B,T,36)
    float* out_sind = out_alph + (size_t)BB * TT * NOBJ;   // (B,)

    char* wp = (char*)d_ws;
    auto alloc = [&](size_t bytes) -> void* {
        void* r = (void*)wp;
        wp += (bytes + 255) & ~(size_t)255;
        return r;
    };
    int*   sidx  = (int*)alloc(BB * 4);
    int*   slen  = (int*)alloc(BB * 4);
    int*   cnt   = (int*)alloc(32 * 4);
    u16*   objsb = (u16*)alloc((size_t)BB * NOBJ * OBJD * 2);   // 37.75 MB
    u16*   Whcb  = (u16*)alloc((size_t)NHC * 1024 * 2);         // 14.7 MB
    float* bcat  = (float*)alloc(NHC * 4);
    u16*   Wfcb  = (u16*)alloc((size_t)VOCP * 1024 * 2);        // 21 MB
    u16*   Wihb  = (u16*)alloc((size_t)4096 * 3072 * 2);        // 25.2 MB
    float* bsum  = (float*)alloc(4096 * 4);
    u16*   Weab  = (u16*)alloc((size_t)1024 * OBJD * 2);        // 4.2 MB
    u16*   att1b = (u16*)alloc((size_t)BB * NOBJ * ATTD * 2);   // 18.9 MB
    u16*   Xb    = (u16*)alloc((size_t)TT * BB * DECD * 2);     // 10.5 MB
    u16*   Gxb   = (u16*)alloc((size_t)TT * BB * 4096 * 2);     // 41.9 MB
    float* Hcat  = (float*)alloc((size_t)BB * NHC * 4);         // 7.3 MB
    u16*   aweb  = (u16*)alloc((size_t)BB * 2048 * 2);          // 1 MB
    u16*   hball = (u16*)alloc((size_t)TT * BB * DECD * 2);     // 10.5 MB
    float* c     = (float*)alloc((size_t)BB * DECD * 4);        // 1 MB
    (void)ws_size; (void)in_sizes; (void)n_in; (void)out_size;

    sort_kernel<<<1, 256, 0, stream>>>(clen, sidx, slen, cnt, out_len, out_sind);
    meta_kernel<<<20, 256, 0, stream>>>(caps, sidx, out_caps);
    gather_objs<<<BB * NOBJ, 256, 0, stream>>>(objs, sidx, objsb);
    convWhc<<<NHC, 256, 0, stream>>>(Wda, bda, Wfb, bfb, Whh, Whcb, bcat);
    convWfc<<<VOCP, 256, 0, stream>>>(Wfc, Wfcb);
    convWih<<<4096, 256, 0, stream>>>(Wih, bih, bhh, Wihb, bsum);
    convWea<<<1024, 256, 0, stream>>>(Wea, Weab);
    embed_kernel<<<TT * BB, 256, 0, stream>>>(enc, caps, emb, sidx, Xb);
    zero_c<<<256, 256, 0, stream>>>(c);
    hcat0_kernel<<<dim3(7, 256), 256, 0, stream>>>(bcat, Hcat);

    // att1 (bf16): M=9216, N=1024, K=2048
    gemm128<3><<<dim3(8, 72), 256, 0, stream>>>(
        objsb, OBJD, Weab, OBJD, bea, nullptr, att1b, ATTD,
        ATTD, OBJD, 0, nullptr);

    // Gx = X @ Wih[:, :1024]^T + bsum (bf16, gate-interleaved): M=5120, N=4096
    gemm128<3><<<dim3(32, 40), 256, 0, stream>>>(
        Xb, DECD, Wihb, 3072, bsum, nullptr, Gxb, 4096,
        4096, DECD, 0, nullptr);

    for (int t = 0; t < TT; ++t) {
        attn_kernel<<<dim3(BB, 2), 256, 0, stream>>>(
            att1b, Hcat, objsb, wfa, bfa, slen, t, out_alph, aweb);
        // G2 + LSTM fused: h(t) -> hball[t]
        g2l_kernel<<<64, 256, 0, stream>>>(
            aweb, Wihb, Gxb + (size_t)t * BB * 4096, Hcat, c,
            hball + (size_t)t * BB * DECD, cnt + t);
        // Hcat(t+1) = h(t) @ Whc^T + bcat (skip after last step)
        if (t < TT - 1)
            gemm128<8><<<112, 256, 0, stream>>>(
                hball + (size_t)t * BB * DECD, DECD, Whcb, DECD, bcat,
                Hcat, nullptr, NHC, NHC, DECD, 1, cnt + t);
    }

    // batched preds: M=5120, N=10000(pad 10240), K=1024
    preds_gemm<<<3200, 256, 0, stream>>>(hball, Wfcb, bfc, cnt, outP);
}

// Round 12
// 1754.821 us; speedup vs baseline: 1.0870x; 1.0870x over previous
//
#include <hip/hip_runtime.h>
#include <hip/hip_bf16.h>
#include <cstdint>
#include <cstddef>

#define BB 256
#define TT 20
#define NOBJ 36
#define OBJD 2048
#define ATTD 1024
#define DECD 1024
#define VOCAB 10000
#define NHC   7168     // Hcat: 1024 att2 | 2048 gate | 4096 Whh-gates (interleaved)
#define VOCP  10240    // vocab padded to 80 tiles of 128 (8 XCDs x 10 panels)

typedef unsigned short u16;
typedef __attribute__((ext_vector_type(8))) short short8v;
typedef __attribute__((ext_vector_type(4))) float f32x4;

__device__ inline u16 f2bf(float f) {
    __hip_bfloat16 h = __float2bfloat16(f);
    return *reinterpret_cast<u16*>(&h);
}
__device__ inline float bu(u16 u) {
    union { unsigned int i; float f; } x;
    x.i = ((unsigned int)u) << 16;
    return x.f;
}
__device__ inline float sigf(float x) { return 1.f / (1.f + expf(-x)); }

// async global->LDS, 16B per lane (wave-uniform LDS base + lane*16)
__device__ inline void gload16(const u16* g, u16* l) {
    __builtin_amdgcn_global_load_lds(
        (const __attribute__((address_space(1))) unsigned int*)g,
        (__attribute__((address_space(3))) unsigned int*)l, 16, 0, 0);
}

// ---------------------------------------------------------------------------
// Sort: stable descending argsort of lengths (O(B^2), one block)
// ---------------------------------------------------------------------------
__global__ __launch_bounds__(256) void sort_kernel(
    const int* __restrict__ lens, int* __restrict__ sidx, int* __restrict__ slen,
    int* __restrict__ cnt, float* __restrict__ out_len, float* __restrict__ out_sind)
{
    __shared__ int L[BB];
    __shared__ int SL[BB];
    const int i = threadIdx.x;
    const int li = lens[i];
    L[i] = li;
    __syncthreads();
    int r = 0;
    for (int j = 0; j < BB; ++j) {
        const int lj = L[j];
        if (lj > li || (lj == li && j < i)) r++;
    }
    sidx[r] = i;
    slen[r] = li;
    SL[r] = li;
    out_sind[r] = (float)i;
    out_len[r]  = (float)li;
    __syncthreads();
    if (i < TT) {
        int cc = 0;
        for (int b = 0; b < BB; ++b) cc += (SL[b] > i);
        cnt[i] = cc;
    }
}

__global__ __launch_bounds__(256) void meta_kernel(
    const int* __restrict__ caps, const int* __restrict__ sidx,
    float* __restrict__ out_caps)
{
    const int idx = blockIdx.x * 256 + threadIdx.x;   // grid 20
    const int p = idx / TT, t = idx % TT;
    out_caps[idx] = (float)caps[sidx[p] * TT + t];
}

// gather objects in sorted order -> bf16 (9216 x 2048)
__global__ __launch_bounds__(256) void gather_objs(
    const float* __restrict__ objs, const int* __restrict__ sidx,
    u16* __restrict__ objsb)
{
    const int row = blockIdx.x;              // 0..9215
    const int b = row / NOBJ, n = row - b * NOBJ;
    const float* src = objs + ((size_t)sidx[b] * NOBJ + n) * OBJD;
    u16* dst = objsb + (size_t)row * OBJD;
    const int tid = threadIdx.x;
    #pragma unroll
    for (int j = 0; j < 2; ++j) {
        float4 v = ((const float4*)src)[tid + 256 * j];
        ushort4 s;
        s.x = f2bf(v.x); s.y = f2bf(v.y); s.z = f2bf(v.z); s.w = f2bf(v.w);
        ((ushort4*)dst)[tid + 256 * j] = s;
    }
}

// Whc = [Wda | Wfb | Whh gate-interleaved] (7168 x 1024) bf16 + bcat
__global__ __launch_bounds__(256) void convWhc(
    const float* __restrict__ Wda, const float* __restrict__ bda,
    const float* __restrict__ Wfb, const float* __restrict__ bfb,
    const float* __restrict__ Whh,
    u16* __restrict__ Wb, float* __restrict__ bcat)
{
    const int n = blockIdx.x;                // 0..7167
    const int tid = threadIdx.x;
    const float* src;
    float bb = 0.f;
    if (n < 1024)      { src = Wda + (size_t)n * 1024;          bb = bda[n]; }
    else if (n < 3072) { src = Wfb + (size_t)(n - 1024) * 1024; bb = bfb[n - 1024]; }
    else {
        const int loc = n - 3072, q = loc & 3, d = loc >> 2;   // col 3072+4d+q = h.Whh[q*1024+d]
        src = Whh + ((size_t)q * 1024 + d) * 1024;
    }
    float4 v = ((const float4*)src)[tid];
    ushort4 s;
    s.x = f2bf(v.x); s.y = f2bf(v.y); s.z = f2bf(v.z); s.w = f2bf(v.w);
    ((ushort4*)(Wb + (size_t)n * 1024))[tid] = s;
    if (tid == 0) bcat[n] = bb;
}

// Wfc padded (10240 x 1024) bf16
__global__ __launch_bounds__(256) void convWfc(
    const float* __restrict__ Wfc, u16* __restrict__ Wb)
{
    const int n = blockIdx.x;                // 0..10239
    const int tid = threadIdx.x;
    ushort4 s;
    if (n < VOCAB) {
        float4 v = ((const float4*)(Wfc + (size_t)n * 1024))[tid];
        s.x = f2bf(v.x); s.y = f2bf(v.y); s.z = f2bf(v.z); s.w = f2bf(v.w);
    } else { s.x = s.y = s.z = s.w = 0; }
    ((ushort4*)(Wb + (size_t)n * 1024))[tid] = s;
}

// Wih gate-interleaved rows (4096 x 3072) + bsum (interleaved b_ih + b_hh)
__global__ __launch_bounds__(256) void convWih(
    const float* __restrict__ Wih, const float* __restrict__ bih,
    const float* __restrict__ bhh, u16* __restrict__ Wb, float* __restrict__ bsum)
{
    const int n = blockIdx.x;                // 0..4095 ; n = 4d+q
    const int q = n & 3, d = n >> 2;
    const int tid = threadIdx.x;
    const float* src = Wih + ((size_t)q * 1024 + d) * 3072;
    u16* dst = Wb + (size_t)n * 3072;
    #pragma unroll
    for (int j = 0; j < 3; ++j) {
        float4 v = ((const float4*)src)[tid + 256 * j];
        ushort4 s;
        s.x = f2bf(v.x); s.y = f2bf(v.y); s.z = f2bf(v.z); s.w = f2bf(v.w);
        ((ushort4*)dst)[tid + 256 * j] = s;
    }
    if (tid == 0) bsum[n] = bih[q * 1024 + d] + bhh[q * 1024 + d];
}

// Wea (1024 x 2048) bf16
__global__ __launch_bounds__(256) void convWea(
    const float* __restrict__ Wea, u16* __restrict__ Wb)
{
    const int n = blockIdx.x;
    const int tid = threadIdx.x;
    const float* src = Wea + (size_t)n * OBJD;
    u16* dst = Wb + (size_t)n * OBJD;
    #pragma unroll
    for (int j = 0; j < 2; ++j) {
        float4 v = ((const float4*)src)[tid + 256 * j];
        ushort4 s;
        s.x = f2bf(v.x); s.y = f2bf(v.y); s.z = f2bf(v.z); s.w = f2bf(v.w);
        ((ushort4*)dst)[tid + 256 * j] = s;
    }
}

// X[t*B+b] bf16
__global__ __launch_bounds__(256) void embed_kernel(
    const float* __restrict__ enc, const int* __restrict__ caps,
    const float* __restrict__ emb, const int* __restrict__ sidx,
    u16* __restrict__ Xb)
{
    const int blk = blockIdx.x;     // grid T*B
    const int t = blk >> 8;
    const int b = blk & 255;
    const int sb = sidx[b];
    const float* src = (t == 0) ? (enc + (size_t)sb * DECD)
                                : (emb + (size_t)caps[sb * TT + (t - 1)] * DECD);
    const int tid = threadIdx.x;
    float4 v = ((const float4*)src)[tid];
    ushort4 s;
    s.x = f2bf(v.x); s.y = f2bf(v.y); s.z = f2bf(v.z); s.w = f2bf(v.w);
    ((ushort4*)(Xb + (size_t)blk * DECD))[tid] = s;
}

__global__ __launch_bounds__(256) void zero_c(float* __restrict__ c)
{
    ((float4*)c)[blockIdx.x * 256 + threadIdx.x] = make_float4(0.f, 0.f, 0.f, 0.f);
}

// Hcat(0) = broadcast bcat (h0 = 0)
__global__ __launch_bounds__(256) void hcat0_kernel(
    const float* __restrict__ bcat, float* __restrict__ Hcat)
{
    const int col4 = blockIdx.x * 256 + threadIdx.x;   // 0..1791
    const int m = blockIdx.y;
    ((float4*)(Hcat + (size_t)m * NHC))[col4] = ((const float4*)bcat)[col4];
}

// ---------------------------------------------------------------------------
// Shared 128x128xK GEMM core: 3-deep pipelined (counted vmcnt), source-pre-
// swizzled global_load_lds (LDS linear) + swizzled ds_read_b128. K%32==0.
// ---------------------------------------------------------------------------
__device__ __forceinline__ void gemm_core(u16* SH,
    const u16* __restrict__ A, int lda,
    const u16* __restrict__ B, int ldb,
    int K, int m0, int n0, f32x4 acc[4][4])
{
    u16* AsB = SH;
    u16* BsB = SH + 12288;
    const int tid = threadIdx.x;
    const int lane = tid & 63;
    const int w = tid >> 6;
    const int wr = w >> 1, wc = w & 1;

    const int r0 = (w * 2 + 0) * 16 + (lane >> 2);
    const int r1 = (w * 2 + 1) * 16 + (lane >> 2);
    const int s0 = (lane & 3) ^ ((r0 >> 1) & 3);
    const int s1 = (lane & 3) ^ ((r1 >> 1) & 3);
    const u16* gA0 = A + (size_t)(m0 + r0) * lda + s0 * 8;
    const u16* gA1 = A + (size_t)(m0 + r1) * lda + s1 * 8;
    const u16* gB0 = B + (size_t)(n0 + r0) * ldb + s0 * 8;
    const u16* gB1 = B + (size_t)(n0 + r1) * ldb + s1 * 8;
    const int la0 = (w * 2 + 0) * 512;
    const int la1 = (w * 2 + 1) * 512;

    int ia[4], ib[4];
    #pragma unroll
    for (int mi = 0; mi < 4; ++mi) {
        const int r = wr * 64 + mi * 16 + (lane & 15);
        ia[mi] = r * 32 + (((lane >> 4) ^ ((r >> 1) & 3)) << 3);
    }
    #pragma unroll
    for (int nj = 0; nj < 4; ++nj) {
        const int r = wc * 64 + nj * 16 + (lane & 15);
        ib[nj] = r * 32 + (((lane >> 4) ^ ((r >> 1) & 3)) << 3);
    }

    const int nk = K >> 5;
    #pragma unroll
    for (int p = 0; p < 3; ++p) {
        if (p < nk) {
            const int ko = p * 32;
            gload16(gA0 + ko, AsB + p * 4096 + la0);
            gload16(gA1 + ko, AsB + p * 4096 + la1);
            gload16(gB0 + ko, BsB + p * 4096 + la0);
            gload16(gB1 + ko, BsB + p * 4096 + la1);
        }
    }
    int cur = 0;
    for (int it = 0; it < nk; ++it) {
        const int rem = nk - 1 - it;
        if (rem >= 2)      asm volatile("s_waitcnt vmcnt(8)" ::: "memory");
        else if (rem == 1) asm volatile("s_waitcnt vmcnt(4)" ::: "memory");
        else               asm volatile("s_waitcnt vmcnt(0)" ::: "memory");
        __builtin_amdgcn_s_barrier();
        const u16* Asc = AsB + cur * 4096;
        const u16* Bsc = BsB + cur * 4096;
        short8v av[4], bv[4];
        #pragma unroll
        for (int mi = 0; mi < 4; ++mi) av[mi] = *(const short8v*)&Asc[ia[mi]];
        #pragma unroll
        for (int nj = 0; nj < 4; ++nj) bv[nj] = *(const short8v*)&Bsc[ib[nj]];
        __builtin_amdgcn_s_setprio(1);
        #pragma unroll
        for (int mi = 0; mi < 4; ++mi)
            #pragma unroll
            for (int nj = 0; nj < 4; ++nj)
                acc[mi][nj] = __builtin_amdgcn_mfma_f32_16x16x32_bf16(
                    av[mi], bv[nj], acc[mi][nj], 0, 0, 0);
        __builtin_amdgcn_s_setprio(0);
        __builtin_amdgcn_s_barrier();
        if (it + 3 < nk) {
            const int ko = (it + 3) * 32;
            gload16(gA0 + ko, AsB + cur * 4096 + la0);
            gload16(gA1 + ko, AsB + cur * 4096 + la1);
            gload16(gB0 + ko, BsB + cur * 4096 + la0);
            gload16(gB1 + ko, BsB + cur * 4096 + la1);
        }
        cur = (cur == 2) ? 0 : cur + 1;
    }
}

// ---------------------------------------------------------------------------
// Generic GEMM kernel (f32 Cf or bf16 Cb).
// ppx > 0: XCD-aware 1D map — x=bid&7, j=bid>>3, panel = x*ppx + (j>>1),
// m = j&1 (both m-tiles of a panel on one XCD). ppx == 0: 2D grid.
// cntp: skip whole tile when m0 >= *cntp.
// ---------------------------------------------------------------------------
__global__ __launch_bounds__(256) void gemm128(
    const u16* __restrict__ A, int lda,
    const u16* __restrict__ B, int ldb,
    const float* __restrict__ bias,
    float* __restrict__ Cf, u16* __restrict__ Cb, int ldc,
    int Nreal, int K, int ppx, const int* __restrict__ cntp)
{
    __shared__ __align__(16) u16 SH[24576];
    int nIdx, mIdx;
    if (ppx > 0) {
        const int x = blockIdx.x & 7, j = blockIdx.x >> 3;
        nIdx = x * ppx + (j >> 1);
        mIdx = j & 1;
    } else {
        nIdx = blockIdx.x;
        mIdx = blockIdx.y;
    }
    const int m0 = mIdx * 128;
    const int n0 = nIdx * 128;
    if (cntp && m0 >= *cntp) return;

    f32x4 acc[4][4];
    #pragma unroll
    for (int i = 0; i < 4; ++i)
        #pragma unroll
        for (int j = 0; j < 4; ++j) acc[i][j] = (f32x4){0.f, 0.f, 0.f, 0.f};
    gemm_core(SH, A, lda, B, ldb, K, m0, n0, acc);

    const int lane = threadIdx.x & 63, w = threadIdx.x >> 6;
    const int wr = w >> 1, wc = w & 1;
    #pragma unroll
    for (int mi = 0; mi < 4; ++mi) {
        const int mbase = m0 + wr * 64 + mi * 16 + ((lane >> 4) << 2);
        #pragma unroll
        for (int nj = 0; nj < 4; ++nj) {
            const int n = n0 + wc * 64 + nj * 16 + (lane & 15);
            if (n >= Nreal) continue;
            const float bval = bias ? bias[n] : 0.f;
            #pragma unroll
            for (int r = 0; r < 4; ++r) {
                const int m = mbase + r;
                const float v = acc[mi][nj][r] + bval;
                if (Cb) Cb[(size_t)m * ldc + n] = f2bf(v);
                else    Cf[(size_t)m * ldc + n] = v;
            }
        }
    }
}

// ---------------------------------------------------------------------------
// G2 GEMM + fused LSTM. Grid 64, XCD-aware: x=bid&7, j=bid>>3 (0..7),
// panel = x*4 + (j>>1) (0..31), m = j&1 — both m of a Wih panel on one XCD.
// ---------------------------------------------------------------------------
__global__ __launch_bounds__(256) void g2l_kernel(
    const u16* __restrict__ aweb, const u16* __restrict__ Wihb,
    const u16* __restrict__ Gxb_t, const float* __restrict__ Hcat,
    float* __restrict__ c, u16* __restrict__ hb_t,
    const int* __restrict__ cntp)
{
    __shared__ __align__(16) u16 SH[24576];
    const int tid = threadIdx.x;
    const int x = blockIdx.x & 7, j = blockIdx.x >> 3;
    const int n0 = (x * 4 + (j >> 1)) * 128;
    const int m0 = (j & 1) * 128;
    const int act = *cntp;
    if (m0 >= act) return;

    f32x4 acc[4][4];
    #pragma unroll
    for (int i = 0; i < 4; ++i)
        #pragma unroll
        for (int jj = 0; jj < 4; ++jj) acc[i][jj] = (f32x4){0.f, 0.f, 0.f, 0.f};
    gemm_core(SH, aweb, 2048, Wihb + 1024, 3072, 2048, m0, n0, acc);

    const int lane = tid & 63, w = tid >> 6;
    const int wr = w >> 1, wc = w & 1;
    float* patch = (float*)SH;   // 64 x 128 f32 = 32KB (gemm_core done)
    #pragma unroll
    for (int half = 0; half < 2; ++half) {
        __syncthreads();
        if (wr == half) {
            #pragma unroll
            for (int mi = 0; mi < 4; ++mi) {
                const int rbase = mi * 16 + ((lane >> 4) << 2);
                #pragma unroll
                for (int nj = 0; nj < 4; ++nj) {
                    const int col = wc * 64 + nj * 16 + (lane & 15);
                    #pragma unroll
                    for (int r = 0; r < 4; ++r)
                        patch[(rbase + r) * 128 + col] = acc[mi][nj][r];
                }
            }
        }
        __syncthreads();
        const int h0 = half * 64;
        #pragma unroll
        for (int p8 = 0; p8 < 8; ++p8) {
            const int idx = p8 * 256 + tid;
            const int row = idx >> 5, dl = idx & 31;
            const int b = m0 + h0 + row;
            if (b >= act) continue;
            const int d = (n0 >> 2) + dl;
            const float* pr = patch + row * 128 + dl * 4;
            float gi = pr[0], gf = pr[1], gg = pr[2], go = pr[3];
            const ushort4 xv = *(const ushort4*)(Gxb_t + (size_t)b * 4096 + n0 + dl * 4);
            gi += bu(xv.x); gf += bu(xv.y); gg += bu(xv.z); go += bu(xv.w);
            const float4 hv = *(const float4*)(Hcat + (size_t)b * NHC + 3072 + n0 + dl * 4);
            gi += hv.x; gf += hv.y; gg += hv.z; go += hv.w;
            float* cp = c + (size_t)b * 1024 + d;
            const float cn = sigf(gf) * cp[0] + sigf(gi) * tanhf(gg);
            const float hn = sigf(go) * tanhf(cn);
            cp[0] = cn;
            hb_t[(size_t)b * 1024 + d] = f2bf(hn);
        }
    }
}

// ---------------------------------------------------------------------------
// Batched predictions GEMM, XCD-aware: XCD x owns n-panels [10x, 10x+10)
// (2.56MB, L2-resident); A streams. Grid 3200 = 8 x 40m x 10p.
// ---------------------------------------------------------------------------
__global__ __launch_bounds__(256) void preds_gemm(
    const u16* __restrict__ hball, const u16* __restrict__ Wfcb,
    const float* __restrict__ bfc, const int* __restrict__ cnt,
    float* __restrict__ outP)
{
    __shared__ __align__(16) u16 SH[24576];
    const int bid = blockIdx.x;              // 0..3199
    const int x = bid & 7;                   // XCD
    const int j = bid >> 3;                  // 0..399
    const int n0 = (x * 10 + (j % 10)) * 128;
    const int m0 = (j / 10) * 128;           // 0..5119 (row in hball)
    const int t = m0 >> 8;
    const int act = cnt[t];
    const int bbase = m0 & 255;

    f32x4 acc[4][4];
    #pragma unroll
    for (int i = 0; i < 4; ++i)
        #pragma unroll
        for (int jj = 0; jj < 4; ++jj) acc[i][jj] = (f32x4){0.f, 0.f, 0.f, 0.f};
    if (bbase < act)
        gemm_core(SH, hball, 1024, Wfcb, 1024, 1024, m0, n0, acc);

    const int lane = threadIdx.x & 63, w = threadIdx.x >> 6;
    const int wr = w >> 1, wc = w & 1;
    #pragma unroll
    for (int mi = 0; mi < 4; ++mi) {
        const int mbase = bbase + wr * 64 + mi * 16 + ((lane >> 4) << 2);
        #pragma unroll
        for (int nj = 0; nj < 4; ++nj) {
            const int n = n0 + wc * 64 + nj * 16 + (lane & 15);
            if (n >= VOCAB) continue;
            const float bval = bfc[n];
            #pragma unroll
            for (int r = 0; r < 4; ++r) {
                const int b = mbase + r;
                outP[((size_t)b * TT + t) * VOCAB + n] =
                    (b < act) ? (acc[mi][nj][r] + bval) : 0.f;
            }
        }
    }
}

// ---------------------------------------------------------------------------
// Attention, z-split over obj dims, XCD-aware 1D grid 512:
// x=bid&7, j=bid>>3 (0..63): b = x*32 + (j>>1), z = j&1 — both z of a row
// land on one XCD so its att1 row is read once per L2.
// ---------------------------------------------------------------------------
__global__ __launch_bounds__(256) void attn_kernel(
    const u16* __restrict__ att1b, const float* __restrict__ Hcat,
    const u16* __restrict__ objsb,
    const float* __restrict__ wfa, const float* __restrict__ bfa,
    const int* __restrict__ slen, int t,
    float* __restrict__ out_alph, u16* __restrict__ aweb)
{
    const int x = blockIdx.x & 7, j = blockIdx.x >> 3;
    const int b = x * 32 + (j >> 1);
    const int z = j & 1;
    const int tid = threadIdx.x;
    const bool active = t < slen[b];
    if (!active) {
        if (z == 0 && tid < NOBJ)
            out_alph[((size_t)b * TT + t) * NOBJ + tid] = 0.f;
        return;
    }
    __shared__ float wred[4][40];
    __shared__ float es[40];
    __shared__ float alph[40];
    const int lane = tid & 63, w = tid >> 6;
    const float* hrow = Hcat + (size_t)b * NHC;
    const float4 h4 = ((const float4*)hrow)[tid];
    const float4 w4 = ((const float4*)wfa)[tid];
    const u16* a1base = att1b + (size_t)b * NOBJ * ATTD;

    float ep[NOBJ];
    #pragma unroll
    for (int n = 0; n < NOBJ; ++n) {
        ushort4 a4 = ((const ushort4*)(a1base + (size_t)n * ATTD))[tid];
        const float v0 = fmaxf(bu(a4.x) + h4.x, 0.f);
        const float v1 = fmaxf(bu(a4.y) + h4.y, 0.f);
        const float v2 = fmaxf(bu(a4.z) + h4.z, 0.f);
        const float v3 = fmaxf(bu(a4.w) + h4.w, 0.f);
        ep[n] = v0 * w4.x + v1 * w4.y + v2 * w4.z + v3 * w4.w;
    }
    #pragma unroll
    for (int n = 0; n < NOBJ; ++n) {
        float p = ep[n];
        #pragma unroll
        for (int off = 32; off > 0; off >>= 1) p += __shfl_down(p, off, 64);
        if (lane == 0) wred[w][n] = p;
    }
    __syncthreads();
    if (tid < NOBJ)
        es[tid] = wred[0][tid] + wred[1][tid] + wred[2][tid] + wred[3][tid] + bfa[0];
    __syncthreads();
    if (tid < 64) {
        float mv = (tid < NOBJ) ? es[tid] : -1e30f;
        #pragma unroll
        for (int off = 32; off > 0; off >>= 1) mv = fmaxf(mv, __shfl_xor(mv, off, 64));
        float e = (tid < NOBJ) ? expf(es[tid] - mv) : 0.f;
        float s = e;
        #pragma unroll
        for (int off = 32; off > 0; off >>= 1) s += __shfl_xor(s, off, 64);
        if (tid < NOBJ) alph[tid] = e / s;
    }
    __syncthreads();
    if (z == 0 && tid < NOBJ)
        out_alph[((size_t)b * TT + t) * NOBJ + tid] = alph[tid];

    float acc[4] = {0.f, 0.f, 0.f, 0.f};
    const u16* ob = objsb + (size_t)b * NOBJ * OBJD + z * 1024 + tid * 4;
    #pragma unroll 4
    for (int n = 0; n < NOBJ; ++n) {
        const ushort4 ov = *(const ushort4*)(ob + (size_t)n * OBJD);
        const float al = alph[n];
        acc[0] = fmaf(al, bu(ov.x), acc[0]);
        acc[1] = fmaf(al, bu(ov.y), acc[1]);
        acc[2] = fmaf(al, bu(ov.z), acc[2]);
        acc[3] = fmaf(al, bu(ov.w), acc[3]);
    }
    const float4 g0 = *(const float4*)(hrow + 1024 + z * 1024 + tid * 4);
    ushort4 st;
    st.x = f2bf(acc[0] * sigf(g0.x));
    st.y = f2bf(acc[1] * sigf(g0.y));
    st.z = f2bf(acc[2] * sigf(g0.z));
    st.w = f2bf(acc[3] * sigf(g0.w));
    *(ushort4*)&aweb[(size_t)b * 2048 + z * 1024 + tid * 4] = st;
}

// ---------------------------------------------------------------------------
extern "C" void kernel_launch(void* const* d_in, const int* in_sizes, int n_in,
                              void* d_out, int out_size, void* d_ws, size_t ws_size,
                              hipStream_t stream)
{
    const float* enc  = (const float*)d_in[0];
    const float* objs = (const float*)d_in[1];
    const int*   caps = (const int*)d_in[2];
    const int*   clen = (const int*)d_in[3];
    const float* emb  = (const float*)d_in[4];
    const float* Wea  = (const float*)d_in[5];
    const float* bea  = (const float*)d_in[6];
    const float* Wda  = (const float*)d_in[7];
    const float* bda  = (const float*)d_in[8];
    const float* wfa  = (const float*)d_in[9];
    const float* bfa  = (const float*)d_in[10];
    const float* Wfb  = (const float*)d_in[11];
    const float* bfb  = (const float*)d_in[12];
    const float* Wih  = (const float*)d_in[13];
    const float* Whh  = (const float*)d_in[14];
    const float* bih  = (const float*)d_in[15];
    const float* bhh  = (const float*)d_in[16];
    const float* Wfc  = (const float*)d_in[17];
    const float* bfc  = (const float*)d_in[18];

    float* outP     = (float*)d_out;                       // (B,T,V)
    float* out_caps = outP + (size_t)BB * TT * VOCAB;      // (B,T)
    float* out_len  = out_caps + BB * TT;                  // (B,)
    float* out_alph = out_len + BB;                        // (B,T,36)
    float* out_sind = out_alph + (size_t)BB * TT * NOBJ;   // (B,)

    char* wp = (char*)d_ws;
    auto alloc = [&](size_t bytes) -> void* {
        void* r = (void*)wp;
        wp += (bytes + 255) & ~(size_t)255;
        return r;
    };
    int*   sidx  = (int*)alloc(BB * 4);
    int*   slen  = (int*)alloc(BB * 4);
    int*   cnt   = (int*)alloc(32 * 4);
    u16*   objsb = (u16*)alloc((size_t)BB * NOBJ * OBJD * 2);   // 37.75 MB
    u16*   Whcb  = (u16*)alloc((size_t)NHC * 1024 * 2);         // 14.7 MB
    float* bcat  = (float*)alloc(NHC * 4);
    u16*   Wfcb  = (u16*)alloc((size_t)VOCP * 1024 * 2);        // 21 MB
    u16*   Wihb  = (u16*)alloc((size_t)4096 * 3072 * 2);        // 25.2 MB
    float* bsum  = (float*)alloc(4096 * 4);
    u16*   Weab  = (u16*)alloc((size_t)1024 * OBJD * 2);        // 4.2 MB
    u16*   att1b = (u16*)alloc((size_t)BB * NOBJ * ATTD * 2);   // 18.9 MB
    u16*   Xb    = (u16*)alloc((size_t)TT * BB * DECD * 2);     // 10.5 MB
    u16*   Gxb   = (u16*)alloc((size_t)TT * BB * 4096 * 2);     // 41.9 MB
    float* Hcat  = (float*)alloc((size_t)BB * NHC * 4);         // 7.3 MB
    u16*   aweb  = (u16*)alloc((size_t)BB * 2048 * 2);          // 1 MB
    u16*   hball = (u16*)alloc((size_t)TT * BB * DECD * 2);     // 10.5 MB
    float* c     = (float*)alloc((size_t)BB * DECD * 4);        // 1 MB
    (void)ws_size; (void)in_sizes; (void)n_in; (void)out_size;

    sort_kernel<<<1, 256, 0, stream>>>(clen, sidx, slen, cnt, out_len, out_sind);
    meta_kernel<<<20, 256, 0, stream>>>(caps, sidx, out_caps);
    gather_objs<<<BB * NOBJ, 256, 0, stream>>>(objs, sidx, objsb);
    convWhc<<<NHC, 256, 0, stream>>>(Wda, bda, Wfb, bfb, Whh, Whcb, bcat);
    convWfc<<<VOCP, 256, 0, stream>>>(Wfc, Wfcb);
    convWih<<<4096, 256, 0, stream>>>(Wih, bih, bhh, Wihb, bsum);
    convWea<<<1024, 256, 0, stream>>>(Wea, Weab);
    embed_kernel<<<TT * BB, 256, 0, stream>>>(enc, caps, emb, sidx, Xb);
    zero_c<<<256, 256, 0, stream>>>(c);
    hcat0_kernel<<<dim3(7, 256), 256, 0, stream>>>(bcat, Hcat);

    // att1 (bf16): M=9216, N=1024, K=2048
    gemm128<<<dim3(8, 72), 256, 0, stream>>>(
        objsb, OBJD, Weab, OBJD, bea, nullptr, att1b, ATTD,
        ATTD, OBJD, 0, nullptr);

    // Gx = X @ Wih[:, :1024]^T + bsum (bf16, gate-interleaved): M=5120, N=4096
    gemm128<<<dim3(32, 40), 256, 0, stream>>>(
        Xb, DECD, Wihb, 3072, bsum, nullptr, Gxb, 4096,
        4096, DECD, 0, nullptr);

    for (int t = 0; t < TT; ++t) {
        // attn: XCD-aware 1D grid 512 (z-pair of a row on one XCD)
        attn_kernel<<<512, 256, 0, stream>>>(
            att1b, Hcat, objsb, wfa, bfa, slen, t, out_alph, aweb);
        // G2 + LSTM fused: h(t) -> hball[t] (XCD-aware, 64 blocks)
        g2l_kernel<<<64, 256, 0, stream>>>(
            aweb, Wihb, Gxb + (size_t)t * BB * 4096, Hcat, c,
            hball + (size_t)t * BB * DECD, cnt + t);
        // Hcat(t+1) = h(t) @ Whc^T + bcat (XCD-aware ppx=7, 112 blocks)
        if (t < TT - 1)
            gemm128<<<112, 256, 0, stream>>>(
                hball + (size_t)t * BB * DECD, DECD, Whcb, DECD, bcat,
                Hcat, nullptr, NHC, NHC, DECD, 7, cnt + t);
    }

    // batched preds: M=5120, N=10000(pad 10240), K=1024
    preds_gemm<<<3200, 256, 0, stream>>>(hball, Wfcb, bfc, cnt, outP);
}